// Round 1
// baseline (3555.922 us; speedup 1.0000x reference)
//
#include <hip/hip_runtime.h>
#include <stdint.h>

#define DI __device__ __forceinline__

static constexpr int B   = 4;
static constexpr int N   = 8192;
static constexpr int M   = 2048;
static constexpr int KNN = 16;
static constexpr int O   = 64;
static constexpr int E   = 65;   // 2C+1 edge channels

DI float fadd(float a, float b){ return __fadd_rn(a,b); }
DI float fsub(float a, float b){ return __fsub_rn(a,b); }
DI float fmul(float a, float b){ return __fmul_rn(a,b); }

// ---------------- K0a: feat (B,96,N) -> featT (B,N,96) ----------------
__global__ __launch_bounds__(256) void k_transpose(const float* __restrict__ feat,
                                                   float* __restrict__ featT){
  __shared__ float tile[64*97];
  int blk = blockIdx.x;                 // B*(N/64) blocks
  int b = blk / (N/64);
  int n0 = (blk % (N/64)) * 64;
  const float* fb = feat + (size_t)b*96*N;
  for (int e = threadIdx.x; e < 96*64; e += 256){
    int cv = e >> 6, nn = e & 63;
    tile[nn*97 + cv] = fb[(size_t)cv*N + n0 + nn];
  }
  __syncthreads();
  float* ob = featT + ((size_t)b*N + n0)*96;
  for (int e = threadIdx.x; e < 96*64; e += 256){
    int nn = e / 96, cv = e - nn*96;
    ob[e] = tile[nn*97 + cv];
  }
}

// ---------------- K0b: xyz -> SoA + per-point squared norms ----------------
__global__ __launch_bounds__(256) void k_xyz_pre(const float* __restrict__ xyz,
                                                 float* __restrict__ xsoa,
                                                 float* __restrict__ sx){
  int i = blockIdx.x*256 + threadIdx.x;
  if (i >= B*N) return;
  int b = i >> 13, n = i & 8191;
  float x = xyz[(size_t)i*3+0], y = xyz[(size_t)i*3+1], z = xyz[(size_t)i*3+2];
  xsoa[((size_t)b*3+0)*N + n] = x;
  xsoa[((size_t)b*3+1)*N + n] = y;
  xsoa[((size_t)b*3+2)*N + n] = z;
  sx[i] = fadd(fadd(fmul(x,x),fmul(y,y)),fmul(z,z));   // numpy order ((x2+y2)+z2)
}

// ---------------- K1: farthest point sampling (exact numpy semantics) ----------------
__global__ __launch_bounds__(1024) void k_fps(const float* __restrict__ xsoa,
                                              int* __restrict__ fps_idx,
                                              float* __restrict__ newxyz){
  int b = blockIdx.x;
  const float* X = xsoa + (size_t)b*3*N;
  __shared__ unsigned long long wred[16];
  __shared__ float cent[3];
  __shared__ int winner;
  int tid = threadIdx.x;
  int lane = tid & 63, wid = tid >> 6;

  float px[8], py[8], pz[8], dist[8];
  #pragma unroll
  for (int j = 0; j < 8; ++j){
    int n = tid*8 + j;
    px[j] = X[n]; py[j] = X[N+n]; pz[j] = X[2*N+n];
    dist[j] = 1e10f;
  }
  if (tid == 0){
    winner = 0;
    cent[0] = X[0]; cent[1] = X[N]; cent[2] = X[2*N];
    fps_idx[b*M] = 0;
    newxyz[(size_t)(b*M)*3+0] = X[0];
    newxyz[(size_t)(b*M)*3+1] = X[N];
    newxyz[(size_t)(b*M)*3+2] = X[2*N];
  }
  __syncthreads();

  for (int it = 1; it < M; ++it){
    float cx = cent[0], cy = cent[1], cz = cent[2];
    float bv = -1.f; int bn = 0;
    #pragma unroll
    for (int j = 0; j < 8; ++j){
      float dx = fsub(px[j], cx), dy = fsub(py[j], cy), dz = fsub(pz[j], cz);
      float d  = fadd(fadd(fmul(dx,dx), fmul(dy,dy)), fmul(dz,dz));  // no FMA, numpy sum order
      float nd = fminf(dist[j], d);
      dist[j] = nd;
      if (nd > bv){ bv = nd; bn = tid*8 + j; }   // ascending j => first-index tie-break
    }
    // pack: max dist, then min index (8191-idx in low bits, max-reduced)
    unsigned long long key = ((unsigned long long)__float_as_uint(bv) << 32) | (unsigned)(8191 - bn);
    #pragma unroll
    for (int s = 1; s < 64; s <<= 1){
      unsigned long long o_ = __shfl_xor(key, s, 64);
      if (o_ > key) key = o_;
    }
    if (lane == 0) wred[wid] = key;
    __syncthreads();
    if (wid == 0){
      unsigned long long k2 = (lane < 16) ? wred[lane] : 0ull;
      #pragma unroll
      for (int s = 1; s < 16; s <<= 1){
        unsigned long long o_ = __shfl_xor(k2, s, 64);
        if (o_ > k2) k2 = o_;
      }
      if (lane == 0){
        int idx = 8191 - (int)(unsigned)(k2 & 0xFFFFFFFFull);
        winner = idx;
        fps_idx[b*M + it] = idx;
      }
    }
    __syncthreads();
    int wn = winner;
    if ((wn >> 3) == tid){             // owning thread broadcasts its registers (no dynamic reg index)
      int jw = wn & 7;
      float ox = px[0], oy = py[0], oz = pz[0];
      #pragma unroll
      for (int j = 1; j < 8; ++j){ if (jw == j){ ox = px[j]; oy = py[j]; oz = pz[j]; } }
      cent[0] = ox; cent[1] = oy; cent[2] = oz;
      newxyz[(size_t)(b*M+it)*3+0] = ox;
      newxyz[(size_t)(b*M+it)*3+1] = oy;
      newxyz[(size_t)(b*M+it)*3+2] = oz;
    }
    __syncthreads();
  }
}

// ---------------- K2: brute-force kNN (k=16), one wave per query ----------------
__global__ __launch_bounds__(256) void k_knn(const float* __restrict__ xsoa,
                                             const float* __restrict__ sx,
                                             const float* __restrict__ newxyz,
                                             int* __restrict__ gidx){
  __shared__ unsigned long long heap[4][64][17];
  __shared__ unsigned long long outk[4][16];
  int tid = threadIdx.x;
  int lane = tid & 63, wv = tid >> 6;
  int w = blockIdx.x*4 + wv;                 // query id, B*M total
  int b = w >> 11;
  const float* X  = xsoa + (size_t)b*3*N;
  const float* SX = sx   + (size_t)b*N;
  float qx = newxyz[(size_t)w*3+0], qy = newxyz[(size_t)w*3+1], qz = newxyz[(size_t)w*3+2];
  float sn = fadd(fadd(fmul(qx,qx),fmul(qy,qy)),fmul(qz,qz));

  unsigned long long cand[16];
  #pragma unroll
  for (int i = 0; i < 16; ++i) cand[i] = 0xFFFFFFFFFFFFFFFFull;

  for (int r = 0; r < 128; ++r){
    int n = (r << 6) + lane;
    float p0 = fmul(qx, X[n]), p1 = fmul(qy, X[N+n]), p2 = fmul(qz, X[2*N+n]);
    float dot = fadd(fadd(p0, p1), p2);
    float d2  = fsub(fadd(sn, SX[n]), fmul(2.0f, dot));   // reference expansion, matching op order
    unsigned u = __float_as_uint(d2);
    u ^= ((unsigned)((int)u >> 31)) | 0x80000000u;        // monotone f32->u32 (handles negatives)
    unsigned long long key = ((unsigned long long)u << 32) | (unsigned)n;
    if (key < cand[15]){
      #pragma unroll
      for (int i = 0; i < 16; ++i){                        // branch-free sorted insertion
        unsigned long long a = cand[i];
        bool sw = key < a;
        unsigned long long lo = sw ? key : a;
        unsigned long long hi = sw ? a : key;
        cand[i] = lo; key = hi;
      }
    }
  }
  #pragma unroll
  for (int i = 0; i < 16; ++i) heap[wv][lane][i] = cand[i];
  unsigned long long my = cand[0];
  int head = 0;
  for (int round = 0; round < 16; ++round){                // 16x extract-min across wave
    unsigned long long k = my;
    #pragma unroll
    for (int s = 1; s < 64; s <<= 1){
      unsigned long long o_ = __shfl_xor(k, s, 64);
      if (o_ < k) k = o_;
    }
    if (my == k){                                          // keys unique (contain n)
      ++head;
      my = (head < 16) ? heap[wv][lane][head] : 0xFFFFFFFFFFFFFFFFull;
    }
    if (lane == 0) outk[wv][round] = k;
  }
  __syncthreads();
  if (lane < 16) gidx[(size_t)w*16 + lane] = (int)(unsigned)(outk[wv][lane] & 0xFFFFFFFFull);
}

// ---------------- K3/K5: edge conv. PASSB=0: BN-stat partials. PASSB=1: full VN-LeakyReLU + pool ----------------
template<int PASSB>
__global__ __launch_bounds__(256) void k_conv(const float* __restrict__ featT,
                                              const float* __restrict__ xsoa,
                                              const float* __restrict__ newxyz,
                                              const int*   __restrict__ fps_idx,
                                              const int*   __restrict__ gidx,
                                              const float* __restrict__ Wf,
                                              const float* __restrict__ Wd,
                                              const float* __restrict__ bn_stats,  // mu[64], scale[64]
                                              const float* __restrict__ bn_bias,
                                              float* __restrict__ bn_part,
                                              float* __restrict__ nf){
  __shared__ float sW0[O*E];
  __shared__ float sW1[PASSB ? O*E : 1];
  __shared__ float sE[E*3*KNN];
  __shared__ float sA[96];
  __shared__ float red[3*256];

  int blk = blockIdx.x;                // b*M + m
  int b = blk >> 11, m = blk & 2047;
  int tid = threadIdx.x;

  for (int e = tid; e < O*E; e += 256) sW0[e] = Wf[e];
  if (PASSB){ for (int e = tid; e < O*E; e += 256) sW1[e] = Wd[e]; }
  int aidx = fps_idx[blk];
  if (tid < 96) sA[tid] = featT[((size_t)(b*N) + aidx)*96 + tid];
  __syncthreads();

  #pragma unroll 4
  for (int kk = 0; kk < KNN; ++kk){
    int n = gidx[(size_t)blk*KNN + kk];
    if (tid < 96){
      float fv = featT[((size_t)(b*N) + n)*96 + tid];
      sE[tid*16 + kk]        = fsub(fv, sA[tid]);   // channels 0..31 (diff), cv==c*3+v==tid
      sE[(96 + tid)*16 + kk] = sA[tid];             // channels 32..63 (anchor)
    } else if (tid < 99){
      int v = tid - 96;
      float nx = xsoa[((size_t)(b*3+v))*N + n];
      sE[(192 + v)*16 + kk] = fsub(nx, newxyz[(size_t)blk*3 + v]);  // channel 64 (rel)
    }
  }
  __syncthreads();

  int o  = tid & 63;
  int w0 = tid >> 6;           // kk = w0 + 4r
  float p[4][3] = {};
  float q[4][3] = {};
  for (int c = 0; c < E; ++c){
    float wf = sW0[o*E + c];
    float wd = PASSB ? sW1[o*E + c] : 0.f;
    #pragma unroll
    for (int r = 0; r < 4; ++r){
      int kk = w0 + 4*r;
      #pragma unroll
      for (int v = 0; v < 3; ++v){
        float ev = sE[(c*3+v)*16 + kk];
        p[r][v] = fmaf(wf, ev, p[r][v]);
        if (PASSB) q[r][v] = fmaf(wd, ev, q[r][v]);
      }
    }
  }

  if (!PASSB){
    float s = 0.f, s2 = 0.f;
    #pragma unroll
    for (int r = 0; r < 4; ++r){
      float nrm = fadd(sqrtf(fadd(fadd(fmul(p[r][0],p[r][0]),fmul(p[r][1],p[r][1])),fmul(p[r][2],p[r][2]))), 1e-6f);
      s  = fadd(s, nrm);
      s2 = fadd(s2, fmul(nrm,nrm));
    }
    red[tid] = s; red[256+tid] = s2;
    __syncthreads();
    if (tid < 64){
      float a  = ((red[tid]    +red[tid+64])    +red[tid+128])    +red[tid+192];
      float a2 = ((red[256+tid]+red[256+tid+64])+red[256+tid+128])+red[256+tid+192];
      bn_part[(size_t)blk*128 + tid]      = a;
      bn_part[(size_t)blk*128 + 64 + tid] = a2;
    }
  } else {
    float mu = bn_stats[o], sc = bn_stats[64+o], bb = bn_bias[o];
    float hs[3] = {0.f,0.f,0.f};
    #pragma unroll
    for (int r = 0; r < 4; ++r){
      float nrm = fadd(sqrtf(fadd(fadd(fmul(p[r][0],p[r][0]),fmul(p[r][1],p[r][1])),fmul(p[r][2],p[r][2]))), 1e-6f);
      float nb  = fadd(fmul(fsub(nrm, mu), sc), bb);
      float rn  = nb / nrm;
      float pn0 = fmul(p[r][0], rn), pn1 = fmul(p[r][1], rn), pn2 = fmul(p[r][2], rn);
      float dot = fadd(fadd(fmul(pn0,q[r][0]),fmul(pn1,q[r][1])),fmul(pn2,q[r][2]));
      float dsq = fadd(fadd(fmul(q[r][0],q[r][0]),fmul(q[r][1],q[r][1])),fmul(q[r][2],q[r][2]));
      float t   = dot / fadd(dsq, 1e-6f);
      bool pos  = (dot >= 0.f);
      float pns[3] = {pn0, pn1, pn2};
      #pragma unroll
      for (int v = 0; v < 3; ++v){
        float inner = pos ? pns[v] : fsub(pns[v], fmul(t, q[r][v]));
        float h = fadd(fmul(0.1f, pns[v]), fmul(0.9f, inner));
        hs[v] = fadd(hs[v], h);
      }
    }
    red[tid] = hs[0]; red[256+tid] = hs[1]; red[512+tid] = hs[2];
    __syncthreads();
    if (tid < 64){
      #pragma unroll
      for (int v = 0; v < 3; ++v){
        const float* rv = red + v*256;
        float tot = ((rv[tid]+rv[tid+64])+rv[tid+128])+rv[tid+192];
        nf[(((size_t)(b*64+o))*3 + v)*M + m] = fmul(tot, 0.0625f);  // mean over k=16
      }
    }
  }
}

// ---------------- K4: BN statistics reduction ----------------
__global__ __launch_bounds__(256) void k_bnstats(const float* __restrict__ bn_part,
                                                 const float* __restrict__ bnw,
                                                 float* __restrict__ bn_stats){
  __shared__ float r1[256], r2[256];
  int o = blockIdx.x, tid = threadIdx.x;
  float s = 0.f, s2 = 0.f;
  for (int i = tid; i < B*M; i += 256){
    s  += bn_part[(size_t)i*128 + o];
    s2 += bn_part[(size_t)i*128 + 64 + o];
  }
  r1[tid] = s; r2[tid] = s2;
  __syncthreads();
  for (int off = 128; off > 0; off >>= 1){
    if (tid < off){ r1[tid] += r1[tid+off]; r2[tid] += r2[tid+off]; }
    __syncthreads();
  }
  if (tid == 0){
    float cnt = (float)(B*M*KNN);
    float mu  = r1[0] / cnt;
    float var = r2[0]/cnt - mu*mu;
    if (var < 0.f) var = 0.f;
    bn_stats[o]    = mu;
    bn_stats[64+o] = bnw[o] / sqrtf(var + 1e-5f);
  }
}

// ---------------- K6: per-batch ZCA (f64 moments + Jacobi eigensolver) ----------------
__global__ __launch_bounds__(1024) void k_zca(const float* __restrict__ nf,
                                              float* __restrict__ zca){
  int b = blockIdx.x, tid = threadIdx.x;
  double s1[3] = {0,0,0}, s2[6] = {0,0,0,0,0,0};
  for (int i = tid; i < O*M; i += 1024){
    int o = i >> 11, m = i & 2047;
    const float* base = nf + (((size_t)(b*O+o))*3)*M + m;
    double x = (double)base[0], y = (double)base[M], z = (double)base[2*M];
    s1[0]+=x;   s1[1]+=y;   s1[2]+=z;
    s2[0]+=x*x; s2[1]+=x*y; s2[2]+=x*z; s2[3]+=y*y; s2[4]+=y*z; s2[5]+=z*z;
  }
  #pragma unroll
  for (int s = 1; s < 64; s <<= 1){
    #pragma unroll
    for (int j = 0; j < 3; ++j) s1[j] += __shfl_xor(s1[j], s, 64);
    #pragma unroll
    for (int j = 0; j < 6; ++j) s2[j] += __shfl_xor(s2[j], s, 64);
  }
  __shared__ double red[16][9];
  int wid = tid >> 6, lane = tid & 63;
  if (lane == 0){
    red[wid][0]=s1[0]; red[wid][1]=s1[1]; red[wid][2]=s1[2];
    for (int j = 0; j < 6; ++j) red[wid][3+j] = s2[j];
  }
  __syncthreads();
  if (tid == 0){
    double S1[3]={0,0,0}, S2[6]={0,0,0,0,0,0};
    for (int w_ = 0; w_ < 16; ++w_){
      S1[0]+=red[w_][0]; S1[1]+=red[w_][1]; S1[2]+=red[w_][2];
      for (int j = 0; j < 6; ++j) S2[j]+=red[w_][3+j];
    }
    double Mt = (double)(O*M);
    double denom = Mt + 1e-6;
    double A[3][3];
    A[0][0]=(S2[0]-S1[0]*S1[0]/Mt)/denom + 1e-5;
    A[0][1]=A[1][0]=(S2[1]-S1[0]*S1[1]/Mt)/denom;
    A[0][2]=A[2][0]=(S2[2]-S1[0]*S1[2]/Mt)/denom;
    A[1][1]=(S2[3]-S1[1]*S1[1]/Mt)/denom + 1e-5;
    A[1][2]=A[2][1]=(S2[4]-S1[1]*S1[2]/Mt)/denom;
    A[2][2]=(S2[5]-S1[2]*S1[2]/Mt)/denom + 1e-5;
    double V[3][3]={{1,0,0},{0,1,0},{0,0,1}};
    for (int sweep = 0; sweep < 30; ++sweep){
      double offd = fabs(A[0][1])+fabs(A[0][2])+fabs(A[1][2]);
      if (offd < 1e-15) break;
      for (int pi = 0; pi < 3; ++pi) for (int qi = pi+1; qi < 3; ++qi){
        double apq = A[pi][qi];
        if (fabs(apq) < 1e-18) continue;
        double app = A[pi][pi], aqq = A[qi][qi];
        double theta = (aqq - app)/(2.0*apq);
        double t = ((theta >= 0) ? 1.0 : -1.0)/(fabs(theta) + sqrt(theta*theta + 1.0));
        double cth = 1.0/sqrt(t*t + 1.0), sth = t*cth;
        for (int r_ = 0; r_ < 3; ++r_){
          double arp=A[r_][pi], arq=A[r_][qi];
          A[r_][pi]=cth*arp - sth*arq;
          A[r_][qi]=sth*arp + cth*arq;
        }
        for (int c_ = 0; c_ < 3; ++c_){
          double apc=A[pi][c_], aqc=A[qi][c_];
          A[pi][c_]=cth*apc - sth*aqc;
          A[qi][c_]=sth*apc + cth*aqc;
        }
        for (int r_ = 0; r_ < 3; ++r_){
          double vrp=V[r_][pi], vrq=V[r_][qi];
          V[r_][pi]=cth*vrp - sth*vrq;
          V[r_][qi]=sth*vrp + cth*vrq;
        }
      }
    }
    double wv[3] = {A[0][0], A[1][1], A[2][2]};
    for (int j = 0; j < 3; ++j) if (wv[j] < 1e-5) wv[j] = 1e-5;
    double is[3] = {1.0/sqrt(wv[0]), 1.0/sqrt(wv[1]), 1.0/sqrt(wv[2])};
    for (int i = 0; i < 3; ++i)
      for (int j = 0; j < 3; ++j){
        double wz = V[i][0]*is[0]*V[j][0] + V[i][1]*is[1]*V[j][1] + V[i][2]*is[2]*V[j][2];
        zca[b*12 + i*3 + j] = (float)wz;
      }
    for (int j = 0; j < 3; ++j) zca[b*12 + 9 + j] = (float)(S1[j]/Mt);
  }
}

// ---------------- K7: whiten + gamma ----------------
__global__ __launch_bounds__(256) void k_out(const float* __restrict__ nf,
                                             const float* __restrict__ zca,
                                             const float* __restrict__ gamma,
                                             float* __restrict__ out){
  int i = blockIdx.x*256 + threadIdx.x;   // B*O*M
  if (i >= B*O*M) return;
  int m = i & 2047;
  int bo = i >> 11;
  int o = bo & 63;
  int b = bo >> 6;
  const float* W  = zca + b*12;
  const float* mn = W + 9;
  const float* base = nf + (size_t)bo*3*M + m;
  float c0 = fsub(base[0],   mn[0]);
  float c1 = fsub(base[M],   mn[1]);
  float c2 = fsub(base[2*M], mn[2]);
  float g = gamma[o];
  #pragma unroll
  for (int v = 0; v < 3; ++v){
    float val = fadd(fadd(fmul(W[v*3+0], c0), fmul(W[v*3+1], c1)), fmul(W[v*3+2], c2));
    out[(size_t)bo*3*M + (size_t)v*M + m] = fmul(val, g);
  }
}

extern "C" void kernel_launch(void* const* d_in, const int* in_sizes, int n_in,
                              void* d_out, int out_size, void* d_ws, size_t ws_size,
                              hipStream_t stream){
  const float* xyz  = (const float*)d_in[0];
  const float* feat = (const float*)d_in[1];
  const float* Wf   = (const float*)d_in[2];
  const float* Wd   = (const float*)d_in[3];
  const float* bnw  = (const float*)d_in[4];
  const float* bnb  = (const float*)d_in[5];
  const float* gam  = (const float*)d_in[6];
  float* out      = (float*)d_out;
  float* newxyz   = out;              // (B,M,3)
  float* conv_out = out + (size_t)B*M*3;

  char* ws = (char*)d_ws;
  size_t off = 0;
  auto alloc = [&](size_t bytes)->void*{
    void* p = ws + off;
    off = (off + bytes + 255) & ~(size_t)255;
    return p;
  };
  float* featT    = (float*)alloc((size_t)B*N*96*4);
  float* xsoa     = (float*)alloc((size_t)B*3*N*4);
  float* sx       = (float*)alloc((size_t)B*N*4);
  int*   fpsi     = (int*)  alloc((size_t)B*M*4);
  int*   gidx     = (int*)  alloc((size_t)B*M*KNN*4);
  float* bn_part  = (float*)alloc((size_t)B*M*128*4);
  float* bn_stats = (float*)alloc(128*4);
  float* nf       = (float*)alloc((size_t)B*O*3*M*4);
  float* zca      = (float*)alloc(B*12*4);

  hipLaunchKernelGGL(k_transpose, dim3(B*(N/64)), dim3(256), 0, stream, feat, featT);
  hipLaunchKernelGGL(k_xyz_pre,   dim3(B*N/256),  dim3(256), 0, stream, xyz, xsoa, sx);
  hipLaunchKernelGGL(k_fps,       dim3(B),        dim3(1024),0, stream, xsoa, fpsi, newxyz);
  hipLaunchKernelGGL(k_knn,       dim3(B*M/4),    dim3(256), 0, stream, xsoa, sx, newxyz, gidx);
  hipLaunchKernelGGL((k_conv<0>), dim3(B*M),      dim3(256), 0, stream,
                     featT, xsoa, newxyz, fpsi, gidx, Wf, Wd, bn_stats, bnb, bn_part, nf);
  hipLaunchKernelGGL(k_bnstats,   dim3(O),        dim3(256), 0, stream, bn_part, bnw, bn_stats);
  hipLaunchKernelGGL((k_conv<1>), dim3(B*M),      dim3(256), 0, stream,
                     featT, xsoa, newxyz, fpsi, gidx, Wf, Wd, bn_stats, bnb, bn_part, nf);
  hipLaunchKernelGGL(k_zca,       dim3(B),        dim3(1024),0, stream, nf, zca);
  hipLaunchKernelGGL(k_out,       dim3((B*O*M)/256), dim3(256), 0, stream, nf, zca, gam, conv_out);
}

// Round 2
// 2988.770 us; speedup vs baseline: 1.1898x; 1.1898x over previous
//
#include <hip/hip_runtime.h>
#include <stdint.h>

#define DI __device__ __forceinline__

static constexpr int B   = 4;
static constexpr int N   = 8192;
static constexpr int M   = 2048;
static constexpr int KNN = 16;
static constexpr int O   = 64;
static constexpr int E   = 65;   // 2C+1 edge channels

DI float fadd(float a, float b){ return __fadd_rn(a,b); }
DI float fsub(float a, float b){ return __fsub_rn(a,b); }
DI float fmul(float a, float b){ return __fmul_rn(a,b); }

// ---------------- K0a: feat (B,96,N) -> featT (B,N,96) ----------------
__global__ __launch_bounds__(256) void k_transpose(const float* __restrict__ feat,
                                                   float* __restrict__ featT){
  __shared__ float tile[64*97];
  int blk = blockIdx.x;                 // B*(N/64) blocks
  int b = blk / (N/64);
  int n0 = (blk % (N/64)) * 64;
  const float* fb = feat + (size_t)b*96*N;
  for (int e = threadIdx.x; e < 96*64; e += 256){
    int cv = e >> 6, nn = e & 63;
    tile[nn*97 + cv] = fb[(size_t)cv*N + n0 + nn];
  }
  __syncthreads();
  float* ob = featT + ((size_t)b*N + n0)*96;
  for (int e = threadIdx.x; e < 96*64; e += 256){
    int nn = e / 96, cv = e - nn*96;
    ob[e] = tile[nn*97 + cv];
  }
}

// ---------------- K0b: xyz -> SoA + per-point squared norms ----------------
__global__ __launch_bounds__(256) void k_xyz_pre(const float* __restrict__ xyz,
                                                 float* __restrict__ xsoa,
                                                 float* __restrict__ sx){
  int i = blockIdx.x*256 + threadIdx.x;
  if (i >= B*N) return;
  int b = i >> 13, n = i & 8191;
  float x = xyz[(size_t)i*3+0], y = xyz[(size_t)i*3+1], z = xyz[(size_t)i*3+2];
  xsoa[((size_t)b*3+0)*N + n] = x;
  xsoa[((size_t)b*3+1)*N + n] = y;
  xsoa[((size_t)b*3+2)*N + n] = z;
  sx[i] = fadd(fadd(fmul(x,x),fmul(y,y)),fmul(z,z));   // numpy order ((x2+y2)+z2)
}

// ---------------- K1: farthest point sampling (exact numpy semantics) ----------------
// 256 threads, 32 contiguous points per thread in registers.
// Inner loop tracks VALUE-only max; index recovered by equality scan + ballot
// (thread-contiguous ownership => lowest matching lane == lowest original index,
//  matching numpy argmax first-occurrence).
__global__ __launch_bounds__(256, 1) void k_fps(const float* __restrict__ xsoa,
                                                int* __restrict__ fps_idx,
                                                float* __restrict__ newxyz){
  int b = blockIdx.x;
  const float* X = xsoa + (size_t)b*3*N;
  __shared__ float lx[N], ly[N], lz[N];       // 96 KB, read-only after init
  __shared__ float swv[2][4];
  __shared__ int   swi[2][4];
  int tid = threadIdx.x;
  int lane = tid & 63;
  int wid = tid >> 6;

  for (int j = tid; j < N; j += 256){
    lx[j] = X[j]; ly[j] = X[N+j]; lz[j] = X[2*N+j];
  }
  __syncthreads();

  float px[32], py[32], pz[32], dist[32];
  #pragma unroll
  for (int j = 0; j < 32; ++j){
    int n = tid*32 + j;
    px[j] = lx[n]; py[j] = ly[n]; pz[j] = lz[n];
    dist[j] = 1e10f;
  }
  if (tid == 0){
    fps_idx[b*M] = 0;
    newxyz[(size_t)(b*M)*3+0] = lx[0];
    newxyz[(size_t)(b*M)*3+1] = ly[0];
    newxyz[(size_t)(b*M)*3+2] = lz[0];
  }
  int winner = 0;

  for (int it = 1; it < M; ++it){
    float cx = lx[winner], cy = ly[winner], cz = lz[winner];  // broadcast ds_read
    float vmax = -1.f;
    #pragma unroll
    for (int j = 0; j < 32; ++j){
      float dx = fsub(px[j],cx), dy = fsub(py[j],cy), dz = fsub(pz[j],cz);
      float d  = fadd(fadd(fmul(dx,dx),fmul(dy,dy)),fmul(dz,dz));  // exact numpy op order, no FMA
      float nd = fminf(dist[j], d);
      dist[j] = nd;
      vmax = fmaxf(vmax, nd);
    }
    // wave max (value only)
    float wv_ = vmax;
    #pragma unroll
    for (int s = 1; s < 64; s <<= 1)
      wv_ = fmaxf(wv_, __shfl_xor(wv_, s, 64));
    // first lane whose local max equals the wave max (lowest lane = lowest orig idx)
    unsigned long long mask = __ballot(vmax == wv_);
    int firstlane = __ffsll(mask) - 1;
    int fj = 0;
    #pragma unroll
    for (int j = 31; j >= 0; --j) if (dist[j] == wv_) fj = j;   // first matching j
    int widx_w = __shfl(tid*32 + fj, firstlane, 64);
    if (lane == 0){ swv[it&1][wid] = wv_; swi[it&1][wid] = widx_w; }
    __syncthreads();
    float m0 = swv[it&1][0], m1 = swv[it&1][1], m2 = swv[it&1][2], m3 = swv[it&1][3];
    float gm = fmaxf(fmaxf(m0,m1), fmaxf(m2,m3));
    int gi;
    if      (m0 == gm) gi = swi[it&1][0];     // lowest wave = lowest orig idx
    else if (m1 == gm) gi = swi[it&1][1];
    else if (m2 == gm) gi = swi[it&1][2];
    else               gi = swi[it&1][3];
    winner = gi;
    if (tid == 0){
      fps_idx[b*M+it] = gi;
      newxyz[(size_t)(b*M+it)*3+0] = lx[gi];
      newxyz[(size_t)(b*M+it)*3+1] = ly[gi];
      newxyz[(size_t)(b*M+it)*3+2] = lz[gi];
    }
  }
}

// ---------------- K2: brute-force kNN (k=16), one wave per query ----------------
__global__ __launch_bounds__(256) void k_knn(const float* __restrict__ xsoa,
                                             const float* __restrict__ sx,
                                             const float* __restrict__ newxyz,
                                             int* __restrict__ gidx){
  __shared__ unsigned long long heap[4][64][17];
  __shared__ unsigned long long outk[4][16];
  int tid = threadIdx.x;
  int lane = tid & 63, wv = tid >> 6;
  int w = blockIdx.x*4 + wv;                 // query id, B*M total
  int b = w >> 11;
  const float* X  = xsoa + (size_t)b*3*N;
  const float* SX = sx   + (size_t)b*N;
  float qx = newxyz[(size_t)w*3+0], qy = newxyz[(size_t)w*3+1], qz = newxyz[(size_t)w*3+2];
  float sn = fadd(fadd(fmul(qx,qx),fmul(qy,qy)),fmul(qz,qz));

  unsigned long long cand[16];
  #pragma unroll
  for (int i = 0; i < 16; ++i) cand[i] = 0xFFFFFFFFFFFFFFFFull;

  for (int r = 0; r < 128; ++r){
    int n = (r << 6) + lane;
    float p0 = fmul(qx, X[n]), p1 = fmul(qy, X[N+n]), p2 = fmul(qz, X[2*N+n]);
    float dot = fadd(fadd(p0, p1), p2);
    float d2  = fsub(fadd(sn, SX[n]), fmul(2.0f, dot));   // reference expansion, matching op order
    unsigned u = __float_as_uint(d2);
    u ^= ((unsigned)((int)u >> 31)) | 0x80000000u;        // monotone f32->u32
    unsigned long long key = ((unsigned long long)u << 32) | (unsigned)n;
    if (key < cand[15]){
      #pragma unroll
      for (int i = 0; i < 16; ++i){                        // branch-free sorted insertion
        unsigned long long a = cand[i];
        bool sw = key < a;
        unsigned long long lo = sw ? key : a;
        unsigned long long hi = sw ? a : key;
        cand[i] = lo; key = hi;
      }
    }
  }
  #pragma unroll
  for (int i = 0; i < 16; ++i) heap[wv][lane][i] = cand[i];
  unsigned long long my = cand[0];
  int head = 0;
  for (int round = 0; round < 16; ++round){                // 16x extract-min across wave
    unsigned long long k = my;
    #pragma unroll
    for (int s = 1; s < 64; s <<= 1){
      unsigned long long o_ = __shfl_xor(k, s, 64);
      if (o_ < k) k = o_;
    }
    if (my == k){
      ++head;
      my = (head < 16) ? heap[wv][lane][head] : 0xFFFFFFFFFFFFFFFFull;
    }
    if (lane == 0) outk[wv][round] = k;
  }
  __syncthreads();
  if (lane < 16) gidx[(size_t)w*16 + lane] = (int)(unsigned)(outk[wv][lane] & 0xFFFFFFFFull);
}

// ---------------- K3/K5: edge conv. PASSB=0: BN-stat partials. PASSB=1: full VN-LeakyReLU + pool ----------------
// wave w0 owns contiguous kk = [4*w0, 4*w0+4): edge reads are wave-uniform
// broadcast ds_read_b128 (conflict-free) instead of 4x scalar ds_read_b32.
template<int PASSB>
__global__ __launch_bounds__(256) void k_conv(const float* __restrict__ featT,
                                              const float* __restrict__ xsoa,
                                              const float* __restrict__ newxyz,
                                              const int*   __restrict__ fps_idx,
                                              const int*   __restrict__ gidx,
                                              const float* __restrict__ Wf,
                                              const float* __restrict__ Wd,
                                              const float* __restrict__ bn_stats,  // mu[64], scale[64]
                                              const float* __restrict__ bn_bias,
                                              float* __restrict__ bn_part,
                                              float* __restrict__ nf){
  __shared__ float sW0[O*E];
  __shared__ float sW1[PASSB ? O*E : 1];
  __shared__ __align__(16) float sE[E*3*KNN];
  __shared__ float sA[96];
  __shared__ float red[3*256];

  int blk = blockIdx.x;                // b*M + m
  int b = blk >> 11, m = blk & 2047;
  int tid = threadIdx.x;

  for (int e = tid; e < O*E; e += 256) sW0[e] = Wf[e];
  if (PASSB){ for (int e = tid; e < O*E; e += 256) sW1[e] = Wd[e]; }
  int aidx = fps_idx[blk];
  if (tid < 96) sA[tid] = featT[((size_t)(b*N) + aidx)*96 + tid];
  __syncthreads();

  #pragma unroll 4
  for (int kk = 0; kk < KNN; ++kk){
    int n = gidx[(size_t)blk*KNN + kk];
    if (tid < 96){
      float fv = featT[((size_t)(b*N) + n)*96 + tid];
      sE[tid*16 + kk]        = fsub(fv, sA[tid]);   // channels 0..31 (diff), cv==c*3+v==tid
      sE[(96 + tid)*16 + kk] = sA[tid];             // channels 32..63 (anchor)
    } else if (tid < 99){
      int v = tid - 96;
      float nx = xsoa[((size_t)(b*3+v))*N + n];
      sE[(192 + v)*16 + kk] = fsub(nx, newxyz[(size_t)blk*3 + v]);  // channel 64 (rel)
    }
  }
  __syncthreads();

  int o  = tid & 63;
  int w0 = tid >> 6;           // wave owns kk = 4*w0 + r, r=0..3
  float p[4][3] = {};
  float q[4][3] = {};
  for (int c = 0; c < E; ++c){
    float wf = sW0[o*E + c];
    float wd = PASSB ? sW1[o*E + c] : 0.f;
    #pragma unroll
    for (int v = 0; v < 3; ++v){
      const float4 ev = *reinterpret_cast<const float4*>(&sE[(c*3+v)*16 + 4*w0]);
      const float* evp = reinterpret_cast<const float*>(&ev);
      #pragma unroll
      for (int r = 0; r < 4; ++r){
        p[r][v] = fmaf(wf, evp[r], p[r][v]);
        if (PASSB) q[r][v] = fmaf(wd, evp[r], q[r][v]);
      }
    }
  }

  if (!PASSB){
    float s = 0.f, s2 = 0.f;
    #pragma unroll
    for (int r = 0; r < 4; ++r){
      float nrm = fadd(sqrtf(fadd(fadd(fmul(p[r][0],p[r][0]),fmul(p[r][1],p[r][1])),fmul(p[r][2],p[r][2]))), 1e-6f);
      s  = fadd(s, nrm);
      s2 = fadd(s2, fmul(nrm,nrm));
    }
    red[tid] = s; red[256+tid] = s2;
    __syncthreads();
    if (tid < 64){
      float a  = ((red[tid]    +red[tid+64])    +red[tid+128])    +red[tid+192];
      float a2 = ((red[256+tid]+red[256+tid+64])+red[256+tid+128])+red[256+tid+192];
      bn_part[(size_t)blk*128 + tid]      = a;
      bn_part[(size_t)blk*128 + 64 + tid] = a2;
    }
  } else {
    float mu = bn_stats[o], sc = bn_stats[64+o], bb = bn_bias[o];
    float hs[3] = {0.f,0.f,0.f};
    #pragma unroll
    for (int r = 0; r < 4; ++r){
      float nrm = fadd(sqrtf(fadd(fadd(fmul(p[r][0],p[r][0]),fmul(p[r][1],p[r][1])),fmul(p[r][2],p[r][2]))), 1e-6f);
      float nb  = fadd(fmul(fsub(nrm, mu), sc), bb);
      float rn  = nb / nrm;
      float pn0 = fmul(p[r][0], rn), pn1 = fmul(p[r][1], rn), pn2 = fmul(p[r][2], rn);
      float dot = fadd(fadd(fmul(pn0,q[r][0]),fmul(pn1,q[r][1])),fmul(pn2,q[r][2]));
      float dsq = fadd(fadd(fmul(q[r][0],q[r][0]),fmul(q[r][1],q[r][1])),fmul(q[r][2],q[r][2]));
      float t   = dot / fadd(dsq, 1e-6f);
      bool pos  = (dot >= 0.f);
      float pns[3] = {pn0, pn1, pn2};
      #pragma unroll
      for (int v = 0; v < 3; ++v){
        float inner = pos ? pns[v] : fsub(pns[v], fmul(t, q[r][v]));
        float h = fadd(fmul(0.1f, pns[v]), fmul(0.9f, inner));
        hs[v] = fadd(hs[v], h);
      }
    }
    red[tid] = hs[0]; red[256+tid] = hs[1]; red[512+tid] = hs[2];
    __syncthreads();
    if (tid < 64){
      #pragma unroll
      for (int v = 0; v < 3; ++v){
        const float* rv = red + v*256;
        float tot = ((rv[tid]+rv[tid+64])+rv[tid+128])+rv[tid+192];
        nf[(((size_t)(b*64+o))*3 + v)*M + m] = fmul(tot, 0.0625f);  // mean over k=16
      }
    }
  }
}

// ---------------- K4: BN statistics reduction ----------------
__global__ __launch_bounds__(256) void k_bnstats(const float* __restrict__ bn_part,
                                                 const float* __restrict__ bnw,
                                                 float* __restrict__ bn_stats){
  __shared__ float r1[256], r2[256];
  int o = blockIdx.x, tid = threadIdx.x;
  float s = 0.f, s2 = 0.f;
  for (int i = tid; i < B*M; i += 256){
    s  += bn_part[(size_t)i*128 + o];
    s2 += bn_part[(size_t)i*128 + 64 + o];
  }
  r1[tid] = s; r2[tid] = s2;
  __syncthreads();
  for (int off = 128; off > 0; off >>= 1){
    if (tid < off){ r1[tid] += r1[tid+off]; r2[tid] += r2[tid+off]; }
    __syncthreads();
  }
  if (tid == 0){
    float cnt = (float)(B*M*KNN);
    float mu  = r1[0] / cnt;
    float var = r2[0]/cnt - mu*mu;
    if (var < 0.f) var = 0.f;
    bn_stats[o]    = mu;
    bn_stats[64+o] = bnw[o] / sqrtf(var + 1e-5f);
  }
}

// ---------------- K6: per-batch ZCA (f64 moments + Jacobi eigensolver) ----------------
__global__ __launch_bounds__(1024) void k_zca(const float* __restrict__ nf,
                                              float* __restrict__ zca){
  int b = blockIdx.x, tid = threadIdx.x;
  double s1[3] = {0,0,0}, s2[6] = {0,0,0,0,0,0};
  for (int i = tid; i < O*M; i += 1024){
    int o = i >> 11, m = i & 2047;
    const float* base = nf + (((size_t)(b*O+o))*3)*M + m;
    double x = (double)base[0], y = (double)base[M], z = (double)base[2*M];
    s1[0]+=x;   s1[1]+=y;   s1[2]+=z;
    s2[0]+=x*x; s2[1]+=x*y; s2[2]+=x*z; s2[3]+=y*y; s2[4]+=y*z; s2[5]+=z*z;
  }
  #pragma unroll
  for (int s = 1; s < 64; s <<= 1){
    #pragma unroll
    for (int j = 0; j < 3; ++j) s1[j] += __shfl_xor(s1[j], s, 64);
    #pragma unroll
    for (int j = 0; j < 6; ++j) s2[j] += __shfl_xor(s2[j], s, 64);
  }
  __shared__ double red[16][9];
  int wid = tid >> 6, lane = tid & 63;
  if (lane == 0){
    red[wid][0]=s1[0]; red[wid][1]=s1[1]; red[wid][2]=s1[2];
    for (int j = 0; j < 6; ++j) red[wid][3+j] = s2[j];
  }
  __syncthreads();
  if (tid == 0){
    double S1[3]={0,0,0}, S2[6]={0,0,0,0,0,0};
    for (int w_ = 0; w_ < 16; ++w_){
      S1[0]+=red[w_][0]; S1[1]+=red[w_][1]; S1[2]+=red[w_][2];
      for (int j = 0; j < 6; ++j) S2[j]+=red[w_][3+j];
    }
    double Mt = (double)(O*M);
    double denom = Mt + 1e-6;
    double A[3][3];
    A[0][0]=(S2[0]-S1[0]*S1[0]/Mt)/denom + 1e-5;
    A[0][1]=A[1][0]=(S2[1]-S1[0]*S1[1]/Mt)/denom;
    A[0][2]=A[2][0]=(S2[2]-S1[0]*S1[2]/Mt)/denom;
    A[1][1]=(S2[3]-S1[1]*S1[1]/Mt)/denom + 1e-5;
    A[1][2]=A[2][1]=(S2[4]-S1[1]*S1[2]/Mt)/denom;
    A[2][2]=(S2[5]-S1[2]*S1[2]/Mt)/denom + 1e-5;
    double V[3][3]={{1,0,0},{0,1,0},{0,0,1}};
    for (int sweep = 0; sweep < 30; ++sweep){
      double offd = fabs(A[0][1])+fabs(A[0][2])+fabs(A[1][2]);
      if (offd < 1e-15) break;
      for (int pi = 0; pi < 3; ++pi) for (int qi = pi+1; qi < 3; ++qi){
        double apq = A[pi][qi];
        if (fabs(apq) < 1e-18) continue;
        double app = A[pi][pi], aqq = A[qi][qi];
        double theta = (aqq - app)/(2.0*apq);
        double t = ((theta >= 0) ? 1.0 : -1.0)/(fabs(theta) + sqrt(theta*theta + 1.0));
        double cth = 1.0/sqrt(t*t + 1.0), sth = t*cth;
        for (int r_ = 0; r_ < 3; ++r_){
          double arp=A[r_][pi], arq=A[r_][qi];
          A[r_][pi]=cth*arp - sth*arq;
          A[r_][qi]=sth*arp + cth*arq;
        }
        for (int c_ = 0; c_ < 3; ++c_){
          double apc=A[pi][c_], aqc=A[qi][c_];
          A[pi][c_]=cth*apc - sth*aqc;
          A[qi][c_]=sth*apc + cth*aqc;
        }
        for (int r_ = 0; r_ < 3; ++r_){
          double vrp=V[r_][pi], vrq=V[r_][qi];
          V[r_][pi]=cth*vrp - sth*vrq;
          V[r_][qi]=sth*vrp + cth*vrq;
        }
      }
    }
    double wv[3] = {A[0][0], A[1][1], A[2][2]};
    for (int j = 0; j < 3; ++j) if (wv[j] < 1e-5) wv[j] = 1e-5;
    double is[3] = {1.0/sqrt(wv[0]), 1.0/sqrt(wv[1]), 1.0/sqrt(wv[2])};
    for (int i = 0; i < 3; ++i)
      for (int j = 0; j < 3; ++j){
        double wz = V[i][0]*is[0]*V[j][0] + V[i][1]*is[1]*V[j][1] + V[i][2]*is[2]*V[j][2];
        zca[b*12 + i*3 + j] = (float)wz;
      }
    for (int j = 0; j < 3; ++j) zca[b*12 + 9 + j] = (float)(S1[j]/Mt);
  }
}

// ---------------- K7: whiten + gamma ----------------
__global__ __launch_bounds__(256) void k_out(const float* __restrict__ nf,
                                             const float* __restrict__ zca,
                                             const float* __restrict__ gamma,
                                             float* __restrict__ out){
  int i = blockIdx.x*256 + threadIdx.x;   // B*O*M
  if (i >= B*O*M) return;
  int m = i & 2047;
  int bo = i >> 11;
  int o = bo & 63;
  int b = bo >> 6;
  const float* W  = zca + b*12;
  const float* mn = W + 9;
  const float* base = nf + (size_t)bo*3*M + m;
  float c0 = fsub(base[0],   mn[0]);
  float c1 = fsub(base[M],   mn[1]);
  float c2 = fsub(base[2*M], mn[2]);
  float g = gamma[o];
  #pragma unroll
  for (int v = 0; v < 3; ++v){
    float val = fadd(fadd(fmul(W[v*3+0], c0), fmul(W[v*3+1], c1)), fmul(W[v*3+2], c2));
    out[(size_t)bo*3*M + (size_t)v*M + m] = fmul(val, g);
  }
}

extern "C" void kernel_launch(void* const* d_in, const int* in_sizes, int n_in,
                              void* d_out, int out_size, void* d_ws, size_t ws_size,
                              hipStream_t stream){
  const float* xyz  = (const float*)d_in[0];
  const float* feat = (const float*)d_in[1];
  const float* Wf   = (const float*)d_in[2];
  const float* Wd   = (const float*)d_in[3];
  const float* bnw  = (const float*)d_in[4];
  const float* bnb  = (const float*)d_in[5];
  const float* gam  = (const float*)d_in[6];
  float* out      = (float*)d_out;
  float* newxyz   = out;              // (B,M,3)
  float* conv_out = out + (size_t)B*M*3;

  char* ws = (char*)d_ws;
  size_t off = 0;
  auto alloc = [&](size_t bytes)->void*{
    void* p = ws + off;
    off = (off + bytes + 255) & ~(size_t)255;
    return p;
  };
  float* featT    = (float*)alloc((size_t)B*N*96*4);
  float* xsoa     = (float*)alloc((size_t)B*3*N*4);
  float* sx       = (float*)alloc((size_t)B*N*4);
  int*   fpsi     = (int*)  alloc((size_t)B*M*4);
  int*   gidx     = (int*)  alloc((size_t)B*M*KNN*4);
  float* bn_part  = (float*)alloc((size_t)B*M*128*4);
  float* bn_stats = (float*)alloc(128*4);
  float* nf       = (float*)alloc((size_t)B*O*3*M*4);
  float* zca      = (float*)alloc(B*12*4);

  hipLaunchKernelGGL(k_transpose, dim3(B*(N/64)), dim3(256), 0, stream, feat, featT);
  hipLaunchKernelGGL(k_xyz_pre,   dim3(B*N/256),  dim3(256), 0, stream, xyz, xsoa, sx);
  hipLaunchKernelGGL(k_fps,       dim3(B),        dim3(256), 0, stream, xsoa, fpsi, newxyz);
  hipLaunchKernelGGL(k_knn,       dim3(B*M/4),    dim3(256), 0, stream, xsoa, sx, newxyz, gidx);
  hipLaunchKernelGGL((k_conv<0>), dim3(B*M),      dim3(256), 0, stream,
                     featT, xsoa, newxyz, fpsi, gidx, Wf, Wd, bn_stats, bnb, bn_part, nf);
  hipLaunchKernelGGL(k_bnstats,   dim3(O),        dim3(256), 0, stream, bn_part, bnw, bn_stats);
  hipLaunchKernelGGL((k_conv<1>), dim3(B*M),      dim3(256), 0, stream,
                     featT, xsoa, newxyz, fpsi, gidx, Wf, Wd, bn_stats, bnb, bn_part, nf);
  hipLaunchKernelGGL(k_zca,       dim3(B),        dim3(1024),0, stream, nf, zca);
  hipLaunchKernelGGL(k_out,       dim3((B*O*M)/256), dim3(256), 0, stream, nf, zca, gam, conv_out);
}

// Round 3
// 2349.163 us; speedup vs baseline: 1.5137x; 1.2723x over previous
//
#include <hip/hip_runtime.h>
#include <stdint.h>

#define DI __device__ __forceinline__

static constexpr int B   = 4;
static constexpr int N   = 8192;
static constexpr int M   = 2048;
static constexpr int KNN = 16;
static constexpr int O   = 64;
static constexpr int E   = 65;   // 2C+1 edge channels

typedef float f32x2 __attribute__((ext_vector_type(2)));

DI float fadd(float a, float b){ return __fadd_rn(a,b); }
DI float fsub(float a, float b){ return __fsub_rn(a,b); }
DI float fmul(float a, float b){ return __fmul_rn(a,b); }

// one DPP max step: t = max(t, dpp_perm(t))
template<int CTRL>
DI float dppmax(float v){
  int t = __builtin_amdgcn_update_dpp(0, __float_as_int(v), CTRL, 0xf, 0xf, true);
  return fmaxf(v, __int_as_float(t));
}

// ---------------- K0a: feat (B,96,N) -> featT (B,N,96) ----------------
__global__ __launch_bounds__(256) void k_transpose(const float* __restrict__ feat,
                                                   float* __restrict__ featT){
  __shared__ float tile[64*97];
  int blk = blockIdx.x;                 // B*(N/64) blocks
  int b = blk / (N/64);
  int n0 = (blk % (N/64)) * 64;
  const float* fb = feat + (size_t)b*96*N;
  for (int e = threadIdx.x; e < 96*64; e += 256){
    int cv = e >> 6, nn = e & 63;
    tile[nn*97 + cv] = fb[(size_t)cv*N + n0 + nn];
  }
  __syncthreads();
  float* ob = featT + ((size_t)b*N + n0)*96;
  for (int e = threadIdx.x; e < 96*64; e += 256){
    int nn = e / 96, cv = e - nn*96;
    ob[e] = tile[nn*97 + cv];
  }
}

// ---------------- K0b: xyz -> SoA + per-point squared norms ----------------
__global__ __launch_bounds__(256) void k_xyz_pre(const float* __restrict__ xyz,
                                                 float* __restrict__ xsoa,
                                                 float* __restrict__ sx){
  int i = blockIdx.x*256 + threadIdx.x;
  if (i >= B*N) return;
  int b = i >> 13, n = i & 8191;
  float x = xyz[(size_t)i*3+0], y = xyz[(size_t)i*3+1], z = xyz[(size_t)i*3+2];
  xsoa[((size_t)b*3+0)*N + n] = x;
  xsoa[((size_t)b*3+1)*N + n] = y;
  xsoa[((size_t)b*3+2)*N + n] = z;
  sx[i] = fadd(fadd(fmul(x,x),fmul(y,y)),fmul(z,z));   // numpy order ((x2+y2)+z2)
}

// ---------------- K1: farthest point sampling (exact numpy semantics) ----------------
// 256 threads, 32 contiguous points per thread (16 float2 pairs) in registers.
// Reduce: DPP wave-max (VALU) + readlane + ballot/ffs scalar index recovery —
// no ds_bpermute on the critical path. First-index tie-break preserved:
// contiguous ownership => lowest lane/wave = lowest original index.
__global__ __launch_bounds__(256, 1) void k_fps(const float* __restrict__ xsoa,
                                                int* __restrict__ fps_idx,
                                                float* __restrict__ newxyz){
  #pragma clang fp contract(off)
  int b = blockIdx.x;
  const float* X = xsoa + (size_t)b*3*N;
  __shared__ float lx[N], ly[N], lz[N];       // 96 KB, read-only after init
  __shared__ uint2 swp[2][4];
  int tid = threadIdx.x;
  int lane = tid & 63;
  int wid = tid >> 6;

  for (int j = tid; j < N; j += 256){
    lx[j] = X[j]; ly[j] = X[N+j]; lz[j] = X[2*N+j];
  }
  __syncthreads();

  f32x2 px[16], py[16], pz[16], ds[16];
  const f32x2* lx2 = (const f32x2*)lx;
  const f32x2* ly2 = (const f32x2*)ly;
  const f32x2* lz2 = (const f32x2*)lz;
  #pragma unroll
  for (int i = 0; i < 16; ++i){
    px[i] = lx2[tid*16+i]; py[i] = ly2[tid*16+i]; pz[i] = lz2[tid*16+i];
    ds[i] = (f32x2){1e10f, 1e10f};
  }
  float cx = lx[0], cy = ly[0], cz = lz[0];
  if (tid == 0){
    fps_idx[b*M] = 0;
    newxyz[(size_t)(b*M)*3+0] = cx;
    newxyz[(size_t)(b*M)*3+1] = cy;
    newxyz[(size_t)(b*M)*3+2] = cz;
  }

  for (int it = 1; it < M; ++it){
    f32x2 c2x = (f32x2){cx,cx}, c2y = (f32x2){cy,cy}, c2z = (f32x2){cz,cz};
    float vmA = -1.f, vmB = -1.f;
    #pragma unroll
    for (int i = 0; i < 16; ++i){
      f32x2 dx = px[i] - c2x;                  // IEEE fsub per half (contract off)
      f32x2 dy = py[i] - c2y;
      f32x2 dz = pz[i] - c2z;
      f32x2 s  = (dx*dx + dy*dy) + dz*dz;      // exact numpy sum order per half
      float nx = fminf(ds[i].x, s.x);
      float ny = fminf(ds[i].y, s.y);
      ds[i].x = nx; ds[i].y = ny;
      vmA = fmaxf(vmA, nx); vmB = fmaxf(vmB, ny);
    }
    float vmax = fmaxf(vmA, vmB);

    // local first-index scan (independent of cross-lane reduce)
    int fj = 0;
    #pragma unroll
    for (int i = 15; i >= 0; --i){
      if (ds[i].y == vmax) fj = 2*i+1;
      if (ds[i].x == vmax) fj = 2*i;
    }

    // DPP wave max -> lane 63, then scalar broadcast
    float t = vmax;
    t = dppmax<0xB1>(t);    // quad_perm [1,0,3,2]  (xor 1)
    t = dppmax<0x4E>(t);    // quad_perm [2,3,0,1]  (xor 2)
    t = dppmax<0x141>(t);   // row_half_mirror      (-> max over 8)
    t = dppmax<0x140>(t);   // row_mirror           (-> max over 16)
    t = dppmax<0x142>(t);   // row_bcast15          (-> max over 32 in lanes 16-31/48-63)
    t = dppmax<0x143>(t);   // row_bcast31          (-> full max in lanes 32-63)
    float wm = __int_as_float(__builtin_amdgcn_readlane(__float_as_int(t), 63));

    unsigned long long mask = __ballot(vmax == wm);
    int firstlane = __ffsll(mask) - 1;                      // scalar
    int widx = __builtin_amdgcn_readlane(tid*32 + fj, firstlane);  // wave winner index (uniform)

    int buf = it & 1;
    if (lane == 0) swp[buf][wid] = make_uint2(__float_as_uint(wm), (unsigned)widx);
    __syncthreads();
    unsigned bv = swp[buf][0].x; int gi = (int)swp[buf][0].y;
    #pragma unroll
    for (int w_ = 1; w_ < 4; ++w_){
      unsigned vv = swp[buf][w_].x;
      if (vv > bv){ bv = vv; gi = (int)swp[buf][w_].y; }    // strict > keeps lowest wave on tie
    }
    cx = lx[gi]; cy = ly[gi]; cz = lz[gi];                  // broadcast ds_read
    if (tid == 0){
      fps_idx[b*M+it] = gi;
      newxyz[(size_t)(b*M+it)*3+0] = cx;
      newxyz[(size_t)(b*M+it)*3+1] = cy;
      newxyz[(size_t)(b*M+it)*3+2] = cz;
    }
  }
}

// ---------------- K2: brute-force kNN (k=16), one wave per query ----------------
__global__ __launch_bounds__(256) void k_knn(const float* __restrict__ xsoa,
                                             const float* __restrict__ sx,
                                             const float* __restrict__ newxyz,
                                             int* __restrict__ gidx){
  __shared__ unsigned long long heap[4][64][17];
  __shared__ unsigned long long outk[4][16];
  int tid = threadIdx.x;
  int lane = tid & 63, wv = tid >> 6;
  int w = blockIdx.x*4 + wv;                 // query id, B*M total
  int b = w >> 11;
  const float* X  = xsoa + (size_t)b*3*N;
  const float* SX = sx   + (size_t)b*N;
  float qx = newxyz[(size_t)w*3+0], qy = newxyz[(size_t)w*3+1], qz = newxyz[(size_t)w*3+2];
  float sn = fadd(fadd(fmul(qx,qx),fmul(qy,qy)),fmul(qz,qz));

  unsigned long long cand[16];
  #pragma unroll
  for (int i = 0; i < 16; ++i) cand[i] = 0xFFFFFFFFFFFFFFFFull;

  for (int r = 0; r < 128; ++r){
    int n = (r << 6) + lane;
    float p0 = fmul(qx, X[n]), p1 = fmul(qy, X[N+n]), p2 = fmul(qz, X[2*N+n]);
    float dot = fadd(fadd(p0, p1), p2);
    float d2  = fsub(fadd(sn, SX[n]), fmul(2.0f, dot));   // reference expansion, matching op order
    unsigned u = __float_as_uint(d2);
    u ^= ((unsigned)((int)u >> 31)) | 0x80000000u;        // monotone f32->u32
    unsigned long long key = ((unsigned long long)u << 32) | (unsigned)n;
    if (key < cand[15]){
      #pragma unroll
      for (int i = 0; i < 16; ++i){                        // branch-free sorted insertion
        unsigned long long a = cand[i];
        bool sw = key < a;
        unsigned long long lo = sw ? key : a;
        unsigned long long hi = sw ? a : key;
        cand[i] = lo; key = hi;
      }
    }
  }
  #pragma unroll
  for (int i = 0; i < 16; ++i) heap[wv][lane][i] = cand[i];
  unsigned long long my = cand[0];
  int head = 0;
  for (int round = 0; round < 16; ++round){                // 16x extract-min across wave
    unsigned long long k = my;
    #pragma unroll
    for (int s = 1; s < 64; s <<= 1){
      unsigned long long o_ = __shfl_xor(k, s, 64);
      if (o_ < k) k = o_;
    }
    if (my == k){
      ++head;
      my = (head < 16) ? heap[wv][lane][head] : 0xFFFFFFFFFFFFFFFFull;
    }
    if (lane == 0) outk[wv][round] = k;
  }
  __syncthreads();
  if (lane < 16) gidx[(size_t)w*16 + lane] = (int)(unsigned)(outk[wv][lane] & 0xFFFFFFFFull);
}

// ---------------- K3/K5: edge conv, anchor-folded form ----------------
// p[o,v,kk] = sum_{c<32} Wf[o,c]*neigh[c,v,kk] + AW[o,v] + Wf[o,64]*rel[v,kk]
// where AW[o,v] = sum_c (Wf[o,32+c]-Wf[o,c])*anchor[c,v]  (kk-invariant).
// Staging stores RAW neighbor rows (no subtract) -> single barrier; row stride 20
// floats keeps b128 reads aligned and cuts the 32-way write conflict to 8-way.
template<int PASSB>
__global__ __launch_bounds__(256) void k_conv(const float* __restrict__ featT,
                                              const float* __restrict__ xsoa,
                                              const float* __restrict__ newxyz,
                                              const int*   __restrict__ fps_idx,
                                              const int*   __restrict__ gidx,
                                              const float* __restrict__ Wf,
                                              const float* __restrict__ Wd,
                                              const float* __restrict__ bn_stats,  // mu[64], scale[64]
                                              const float* __restrict__ bn_bias,
                                              float* __restrict__ bn_part,
                                              float* __restrict__ nf){
  __shared__ float sW0[O*E];
  __shared__ float sW1[PASSB ? O*E : 1];
  __shared__ __align__(16) float sNG[99*20];   // rows 0..95: neigh cv; rows 96..98: rel v
  __shared__ float sA[96];
  __shared__ float red[3*256];

  int blk = blockIdx.x;                // b*M + m
  int b = blk >> 11, m = blk & 2047;
  int tid = threadIdx.x;

  for (int e = tid; e < O*E; e += 256) sW0[e] = Wf[e];
  if (PASSB){ for (int e = tid; e < O*E; e += 256) sW1[e] = Wd[e]; }
  int aidx = fps_idx[blk];
  if (tid < 96) sA[tid] = featT[((size_t)(b*N) + aidx)*96 + tid];

  #pragma unroll 4
  for (int kk = 0; kk < KNN; ++kk){
    int n = gidx[(size_t)blk*KNN + kk];
    if (tid < 96){
      sNG[tid*20 + kk] = featT[((size_t)(b*N) + n)*96 + tid];
    } else if (tid < 99){
      int v = tid - 96;
      sNG[(96+v)*20 + kk] = fsub(xsoa[((size_t)(b*3+v))*N + n], newxyz[(size_t)blk*3 + v]);
    }
  }
  __syncthreads();

  int o  = tid & 63;
  int w0 = tid >> 6;           // wave owns kk = 4*w0 + r, r=0..3

  float awf[3] = {0,0,0}, awd[3] = {0,0,0};
  for (int c = 0; c < 32; ++c){
    float df = sW0[o*E+32+c] - sW0[o*E+c];
    float dd = PASSB ? (sW1[o*E+32+c] - sW1[o*E+c]) : 0.f;
    #pragma unroll
    for (int v = 0; v < 3; ++v){
      float a = sA[c*3+v];
      awf[v] = fmaf(df, a, awf[v]);
      if (PASSB) awd[v] = fmaf(dd, a, awd[v]);
    }
  }

  float p[4][3], q[4][3];
  {
    float wr  = sW0[o*E+64];
    float wrd = PASSB ? sW1[o*E+64] : 0.f;
    #pragma unroll
    for (int v = 0; v < 3; ++v){
      const float4 rv = *reinterpret_cast<const float4*>(&sNG[(96+v)*20 + 4*w0]);
      const float* rp = reinterpret_cast<const float*>(&rv);
      #pragma unroll
      for (int r = 0; r < 4; ++r){
        p[r][v] = fmaf(wr, rp[r], awf[v]);
        q[r][v] = PASSB ? fmaf(wrd, rp[r], awd[v]) : 0.f;
      }
    }
  }
  for (int c = 0; c < 32; ++c){
    float wf = sW0[o*E+c];
    float wd = PASSB ? sW1[o*E+c] : 0.f;
    #pragma unroll
    for (int v = 0; v < 3; ++v){
      const float4 ev = *reinterpret_cast<const float4*>(&sNG[(c*3+v)*20 + 4*w0]);
      const float* ep = reinterpret_cast<const float*>(&ev);
      #pragma unroll
      for (int r = 0; r < 4; ++r){
        p[r][v] = fmaf(wf, ep[r], p[r][v]);
        if (PASSB) q[r][v] = fmaf(wd, ep[r], q[r][v]);
      }
    }
  }

  if (!PASSB){
    float s = 0.f, s2 = 0.f;
    #pragma unroll
    for (int r = 0; r < 4; ++r){
      float nrm = fadd(sqrtf(fadd(fadd(fmul(p[r][0],p[r][0]),fmul(p[r][1],p[r][1])),fmul(p[r][2],p[r][2]))), 1e-6f);
      s  = fadd(s, nrm);
      s2 = fadd(s2, fmul(nrm,nrm));
    }
    red[tid] = s; red[256+tid] = s2;
    __syncthreads();
    if (tid < 64){
      float a  = ((red[tid]    +red[tid+64])    +red[tid+128])    +red[tid+192];
      float a2 = ((red[256+tid]+red[256+tid+64])+red[256+tid+128])+red[256+tid+192];
      bn_part[(size_t)blk*128 + tid]      = a;
      bn_part[(size_t)blk*128 + 64 + tid] = a2;
    }
  } else {
    float mu = bn_stats[o], sc = bn_stats[64+o], bb = bn_bias[o];
    float hs[3] = {0.f,0.f,0.f};
    #pragma unroll
    for (int r = 0; r < 4; ++r){
      float nrm = fadd(sqrtf(fadd(fadd(fmul(p[r][0],p[r][0]),fmul(p[r][1],p[r][1])),fmul(p[r][2],p[r][2]))), 1e-6f);
      float nb  = fadd(fmul(fsub(nrm, mu), sc), bb);
      float rn  = nb / nrm;
      float pn0 = fmul(p[r][0], rn), pn1 = fmul(p[r][1], rn), pn2 = fmul(p[r][2], rn);
      float dot = fadd(fadd(fmul(pn0,q[r][0]),fmul(pn1,q[r][1])),fmul(pn2,q[r][2]));
      float dsq = fadd(fadd(fmul(q[r][0],q[r][0]),fmul(q[r][1],q[r][1])),fmul(q[r][2],q[r][2]));
      float t   = dot / fadd(dsq, 1e-6f);
      bool pos  = (dot >= 0.f);
      float pns[3] = {pn0, pn1, pn2};
      #pragma unroll
      for (int v = 0; v < 3; ++v){
        float inner = pos ? pns[v] : fsub(pns[v], fmul(t, q[r][v]));
        float h = fadd(fmul(0.1f, pns[v]), fmul(0.9f, inner));
        hs[v] = fadd(hs[v], h);
      }
    }
    red[tid] = hs[0]; red[256+tid] = hs[1]; red[512+tid] = hs[2];
    __syncthreads();
    if (tid < 64){
      #pragma unroll
      for (int v = 0; v < 3; ++v){
        const float* rv = red + v*256;
        float tot = ((rv[tid]+rv[tid+64])+rv[tid+128])+rv[tid+192];
        nf[(((size_t)(b*64+o))*3 + v)*M + m] = fmul(tot, 0.0625f);  // mean over k=16
      }
    }
  }
}

// ---------------- K4: BN statistics reduction ----------------
__global__ __launch_bounds__(256) void k_bnstats(const float* __restrict__ bn_part,
                                                 const float* __restrict__ bnw,
                                                 float* __restrict__ bn_stats){
  __shared__ float r1[256], r2[256];
  int o = blockIdx.x, tid = threadIdx.x;
  float s = 0.f, s2 = 0.f;
  for (int i = tid; i < B*M; i += 256){
    s  += bn_part[(size_t)i*128 + o];
    s2 += bn_part[(size_t)i*128 + 64 + o];
  }
  r1[tid] = s; r2[tid] = s2;
  __syncthreads();
  for (int off = 128; off > 0; off >>= 1){
    if (tid < off){ r1[tid] += r1[tid+off]; r2[tid] += r2[tid+off]; }
    __syncthreads();
  }
  if (tid == 0){
    float cnt = (float)(B*M*KNN);
    float mu  = r1[0] / cnt;
    float var = r2[0]/cnt - mu*mu;
    if (var < 0.f) var = 0.f;
    bn_stats[o]    = mu;
    bn_stats[64+o] = bnw[o] / sqrtf(var + 1e-5f);
  }
}

// ---------------- K6: per-batch ZCA (f64 moments + Jacobi eigensolver) ----------------
__global__ __launch_bounds__(1024) void k_zca(const float* __restrict__ nf,
                                              float* __restrict__ zca){
  int b = blockIdx.x, tid = threadIdx.x;
  double s1[3] = {0,0,0}, s2[6] = {0,0,0,0,0,0};
  for (int i = tid; i < O*M; i += 1024){
    int o = i >> 11, m = i & 2047;
    const float* base = nf + (((size_t)(b*O+o))*3)*M + m;
    double x = (double)base[0], y = (double)base[M], z = (double)base[2*M];
    s1[0]+=x;   s1[1]+=y;   s1[2]+=z;
    s2[0]+=x*x; s2[1]+=x*y; s2[2]+=x*z; s2[3]+=y*y; s2[4]+=y*z; s2[5]+=z*z;
  }
  #pragma unroll
  for (int s = 1; s < 64; s <<= 1){
    #pragma unroll
    for (int j = 0; j < 3; ++j) s1[j] += __shfl_xor(s1[j], s, 64);
    #pragma unroll
    for (int j = 0; j < 6; ++j) s2[j] += __shfl_xor(s2[j], s, 64);
  }
  __shared__ double red[16][9];
  int wid = tid >> 6, lane = tid & 63;
  if (lane == 0){
    red[wid][0]=s1[0]; red[wid][1]=s1[1]; red[wid][2]=s1[2];
    for (int j = 0; j < 6; ++j) red[wid][3+j] = s2[j];
  }
  __syncthreads();
  if (tid == 0){
    double S1[3]={0,0,0}, S2[6]={0,0,0,0,0,0};
    for (int w_ = 0; w_ < 16; ++w_){
      S1[0]+=red[w_][0]; S1[1]+=red[w_][1]; S1[2]+=red[w_][2];
      for (int j = 0; j < 6; ++j) S2[j]+=red[w_][3+j];
    }
    double Mt = (double)(O*M);
    double denom = Mt + 1e-6;
    double A[3][3];
    A[0][0]=(S2[0]-S1[0]*S1[0]/Mt)/denom + 1e-5;
    A[0][1]=A[1][0]=(S2[1]-S1[0]*S1[1]/Mt)/denom;
    A[0][2]=A[2][0]=(S2[2]-S1[0]*S1[2]/Mt)/denom;
    A[1][1]=(S2[3]-S1[1]*S1[1]/Mt)/denom + 1e-5;
    A[1][2]=A[2][1]=(S2[4]-S1[1]*S1[2]/Mt)/denom;
    A[2][2]=(S2[5]-S1[2]*S1[2]/Mt)/denom + 1e-5;
    double V[3][3]={{1,0,0},{0,1,0},{0,0,1}};
    for (int sweep = 0; sweep < 30; ++sweep){
      double offd = fabs(A[0][1])+fabs(A[0][2])+fabs(A[1][2]);
      if (offd < 1e-15) break;
      for (int pi = 0; pi < 3; ++pi) for (int qi = pi+1; qi < 3; ++qi){
        double apq = A[pi][qi];
        if (fabs(apq) < 1e-18) continue;
        double app = A[pi][pi], aqq = A[qi][qi];
        double theta = (aqq - app)/(2.0*apq);
        double t = ((theta >= 0) ? 1.0 : -1.0)/(fabs(theta) + sqrt(theta*theta + 1.0));
        double cth = 1.0/sqrt(t*t + 1.0), sth = t*cth;
        for (int r_ = 0; r_ < 3; ++r_){
          double arp=A[r_][pi], arq=A[r_][qi];
          A[r_][pi]=cth*arp - sth*arq;
          A[r_][qi]=sth*arp + cth*arq;
        }
        for (int c_ = 0; c_ < 3; ++c_){
          double apc=A[pi][c_], aqc=A[qi][c_];
          A[pi][c_]=cth*apc - sth*aqc;
          A[qi][c_]=sth*apc + cth*aqc;
        }
        for (int r_ = 0; r_ < 3; ++r_){
          double vrp=V[r_][pi], vrq=V[r_][qi];
          V[r_][pi]=cth*vrp - sth*vrq;
          V[r_][qi]=sth*vrp + cth*vrq;
        }
      }
    }
    double wv[3] = {A[0][0], A[1][1], A[2][2]};
    for (int j = 0; j < 3; ++j) if (wv[j] < 1e-5) wv[j] = 1e-5;
    double is[3] = {1.0/sqrt(wv[0]), 1.0/sqrt(wv[1]), 1.0/sqrt(wv[2])};
    for (int i = 0; i < 3; ++i)
      for (int j = 0; j < 3; ++j){
        double wz = V[i][0]*is[0]*V[j][0] + V[i][1]*is[1]*V[j][1] + V[i][2]*is[2]*V[j][2];
        zca[b*12 + i*3 + j] = (float)wz;
      }
    for (int j = 0; j < 3; ++j) zca[b*12 + 9 + j] = (float)(S1[j]/Mt);
  }
}

// ---------------- K7: whiten + gamma ----------------
__global__ __launch_bounds__(256) void k_out(const float* __restrict__ nf,
                                             const float* __restrict__ zca,
                                             const float* __restrict__ gamma,
                                             float* __restrict__ out){
  int i = blockIdx.x*256 + threadIdx.x;   // B*O*M
  if (i >= B*O*M) return;
  int m = i & 2047;
  int bo = i >> 11;
  int o = bo & 63;
  int b = bo >> 6;
  const float* W  = zca + b*12;
  const float* mn = W + 9;
  const float* base = nf + (size_t)bo*3*M + m;
  float c0 = fsub(base[0],   mn[0]);
  float c1 = fsub(base[M],   mn[1]);
  float c2 = fsub(base[2*M], mn[2]);
  float g = gamma[o];
  #pragma unroll
  for (int v = 0; v < 3; ++v){
    float val = fadd(fadd(fmul(W[v*3+0], c0), fmul(W[v*3+1], c1)), fmul(W[v*3+2], c2));
    out[(size_t)bo*3*M + (size_t)v*M + m] = fmul(val, g);
  }
}

extern "C" void kernel_launch(void* const* d_in, const int* in_sizes, int n_in,
                              void* d_out, int out_size, void* d_ws, size_t ws_size,
                              hipStream_t stream){
  const float* xyz  = (const float*)d_in[0];
  const float* feat = (const float*)d_in[1];
  const float* Wf   = (const float*)d_in[2];
  const float* Wd   = (const float*)d_in[3];
  const float* bnw  = (const float*)d_in[4];
  const float* bnb  = (const float*)d_in[5];
  const float* gam  = (const float*)d_in[6];
  float* out      = (float*)d_out;
  float* newxyz   = out;              // (B,M,3)
  float* conv_out = out + (size_t)B*M*3;

  char* ws = (char*)d_ws;
  size_t off = 0;
  auto alloc = [&](size_t bytes)->void*{
    void* p = ws + off;
    off = (off + bytes + 255) & ~(size_t)255;
    return p;
  };
  float* featT    = (float*)alloc((size_t)B*N*96*4);
  float* xsoa     = (float*)alloc((size_t)B*3*N*4);
  float* sx       = (float*)alloc((size_t)B*N*4);
  int*   fpsi     = (int*)  alloc((size_t)B*M*4);
  int*   gidx     = (int*)  alloc((size_t)B*M*KNN*4);
  float* bn_part  = (float*)alloc((size_t)B*M*128*4);
  float* bn_stats = (float*)alloc(128*4);
  float* nf       = (float*)alloc((size_t)B*O*3*M*4);
  float* zca      = (float*)alloc(B*12*4);

  hipLaunchKernelGGL(k_transpose, dim3(B*(N/64)), dim3(256), 0, stream, feat, featT);
  hipLaunchKernelGGL(k_xyz_pre,   dim3(B*N/256),  dim3(256), 0, stream, xyz, xsoa, sx);
  hipLaunchKernelGGL(k_fps,       dim3(B),        dim3(256), 0, stream, xsoa, fpsi, newxyz);
  hipLaunchKernelGGL(k_knn,       dim3(B*M/4),    dim3(256), 0, stream, xsoa, sx, newxyz, gidx);
  hipLaunchKernelGGL((k_conv<0>), dim3(B*M),      dim3(256), 0, stream,
                     featT, xsoa, newxyz, fpsi, gidx, Wf, Wd, bn_stats, bnb, bn_part, nf);
  hipLaunchKernelGGL(k_bnstats,   dim3(O),        dim3(256), 0, stream, bn_part, bnw, bn_stats);
  hipLaunchKernelGGL((k_conv<1>), dim3(B*M),      dim3(256), 0, stream,
                     featT, xsoa, newxyz, fpsi, gidx, Wf, Wd, bn_stats, bnb, bn_part, nf);
  hipLaunchKernelGGL(k_zca,       dim3(B),        dim3(1024),0, stream, nf, zca);
  hipLaunchKernelGGL(k_out,       dim3((B*O*M)/256), dim3(256), 0, stream, nf, zca, gam, conv_out);
}